// Round 7
// baseline (51.021 us; speedup 1.0000x reference)
//
#include <hip/hip_runtime.h>

// Problem constants (from reference setup_inputs)
#define BB  2
#define TT  4
#define CC  256
#define HH  64
#define WW  176
#define NN  900
#define PP  8
#define NTF 3
#define NSF 3

#define HW        (HH * WW)              // 11264
#define NPOINTS   (BB * NN * PP)         // 14400
#define W16       11                     // ceil(176/16) line-buckets along w
#define NBUCKET   (BB * NTF * HH * W16)  // 4224
#define BPF       (HH * W16)             // 704 buckets per (b,frame)
#define SCAN_PER  17                     // 256*17 = 4352 >= 4224
#define GATHER_G  8
#define NGBLK     (NPOINTS / GATHER_G)   // 1800 (fallback path)
#define NBF       (BB * NTF)             // 6 (b,frame) images per cam

// fused pass (round-5 best geometry): block = (cam, bf, h-row); 8 chunks of
// 32 channels staged in padded LDS; points of that (bf,h) bucket write out
// directly (128-B contiguous segments).
#define CCH    32                        // channels per chunk
#define NCH    (CC / CCH)                // 8
#define WPAD   180                       // padded strip stride (floats)
#define CAPM   192                       // cached point-meta capacity (λ≈37.5)

// native vector type
typedef float f32x4 __attribute__((ext_vector_type(4)));

// ws layout (int32 slots)
#define WS_HIST   0
#define WS_OFFS   (WS_HIST + NBUCKET)
#define WS_KEY    (WS_OFFS + NBUCKET + 1)   // +1: sentinel offs[NBUCKET]=NPOINTS
#define WS_RANK   (WS_KEY + NPOINTS)
#define WS_REM    (WS_RANK + NPOINTS)
#define WS_BASE   (WS_REM + NPOINTS)
#define WS_SREM   (WS_BASE + NPOINTS)
#define WS_SBASE  (WS_SREM + NPOINTS)
#define WS_SPT    (WS_SBASE + NPOINTS)
#define WS_INTS   (WS_SPT + NPOINTS)
#define WS_MIN    ((size_t)WS_INTS * 4)

// ---- K0z: zero histogram only (critical path before k1) -------------------
__global__ __launch_bounds__(256) void k0_zero(int* __restrict__ hist)
{
    const int gid = blockIdx.x * 256 + threadIdx.x;
    if (gid < NBUCKET) hist[gid] = 0;
}

// ---- K0p: index passthroughs (as float) — off critical path, after k4 -----
__global__ __launch_bounds__(256) void k0_pass(
    const int* __restrict__ tIdx, const int* __restrict__ sIdx,
    const int* __restrict__ pIdx, float* __restrict__ outIdx)
{
    const int gid = blockIdx.x * 256 + threadIdx.x;
    const int nT = BB * NN * NTF, nS = BB * NN * NSF, nP = NPOINTS;
    if (gid < nT)                 outIdx[gid] = (float)tIdx[gid];
    else if (gid < nT + nS)       outIdx[gid] = (float)sIdx[gid - nT];
    else if (gid < nT + nS + nP)  outIdx[gid] = (float)pIdx[gid - nT - nS];
}

// ---- K1: decode chain, bucket key, histogram ------------------------------
__global__ __launch_bounds__(256) void k1_prep(
    const int* __restrict__ tIdx, const int* __restrict__ sIdx,
    const int* __restrict__ pIdx,
    int* __restrict__ hist, int* __restrict__ key,
    int* __restrict__ rank, int* __restrict__ remArr,
    int* __restrict__ baseArr)
{
    const int pt = blockIdx.x * 256 + threadIdx.x;
    if (pt >= NPOINTS) return;
    const int b  = pt / (NN * PP);
    const int n  = (pt - b * NN * PP) >> 3;     // / PP
    const int bn = b * NN + n;

    const int pi  = pIdx[pt];
    const int s   = pi / (NTF * HW);
    const int rem = pi % HW;                    // h*W + w
    const int h   = rem / WW;
    const int w   = rem - h * WW;

    const int sp    = sIdx[bn * NSF + s];
    const int frame = tIdx[bn * NTF + sp];

    const int base = ((b * TT + frame) * CC) * HW + rem;   // c=0 elem offset
    const int k    = ((b * NTF + frame) * HH + h) * W16 + (w >> 4);
    const int r    = atomicAdd(&hist[k], 1);
    key[pt] = k; rank[pt] = r; remArr[pt] = rem; baseArr[pt] = base;
}

// ---- K2: exclusive scan of 4224 bucket counts (single block, shfl) --------
__global__ __launch_bounds__(256) void k2_scan(
    const int* __restrict__ hist, int* __restrict__ offs)
{
    __shared__ int wsum[4];
    const int t = threadIdx.x;
    const int lane = t & 63, wv = t >> 6;
    int local[SCAN_PER];
    int sum = 0;
    for (int i = 0; i < SCAN_PER; ++i) {
        const int idx = t * SCAN_PER + i;
        const int v = (idx < NBUCKET) ? hist[idx] : 0;
        local[i] = sum;           // exclusive within this thread's chunk
        sum += v;
    }
    // wave-inclusive scan of per-thread sums
    int incl = sum;
    for (int d = 1; d < 64; d <<= 1) {
        const int up = __shfl_up(incl, d, 64);
        if (lane >= d) incl += up;
    }
    if (lane == 63) wsum[wv] = incl;
    __syncthreads();
    int wpre = 0;
    for (int k = 0; k < 4; ++k) if (k < wv) wpre += wsum[k];
    const int base = wpre + incl - sum;   // exclusive prefix of this thread
    for (int i = 0; i < SCAN_PER; ++i) {
        const int idx = t * SCAN_PER + i;
        if (idx < NBUCKET) offs[idx] = base + local[i];
    }
    if (t == 255) offs[NBUCKET] = wpre + incl;  // total = NPOINTS sentinel
}

// ---- K3: scatter points into bucket-sorted order --------------------------
__global__ __launch_bounds__(256) void k3_scatter(
    const int* __restrict__ key, const int* __restrict__ rank,
    const int* __restrict__ remArr, const int* __restrict__ baseArr,
    const int* __restrict__ offs,
    int* __restrict__ sRem, int* __restrict__ sBase, int* __restrict__ sPt)
{
    const int pt = blockIdx.x * 256 + threadIdx.x;
    if (pt >= NPOINTS) return;
    const int pos = offs[key[pt]] + rank[pt];
    sRem[pos]  = remArr[pt];
    sBase[pos] = baseArr[pt];
    sPt[pos]   = pt;
}

// ---- K4 fused: stream (cam,bf,h) strips through LDS, write out directly ---
// Round-5 verified-best geometry. Block (cam, bf, h): for each of 8 chunks
// of 32 channels, stage the 32 strips (176 floats each, padded to 180) in a
// double-buffered LDS tile, then each half-wave writes one point's
// 32-channel out segment (128 B contiguous). Register-staged loads,
// issue-early/write-late; ONE raw barrier per chunk (double-buffer: buffer p
// is rewritten for chunk k+2 only after barrier k+1, which every wave
// reaches only after its chunk-k LDS reads completed via lgkmcnt(0)).

#define LOADR(R, CH) {                                                         \
    const float* s_ = img + (size_t)((CH) * CCH + strip) * HW;                 \
    _Pragma("unroll")                                                          \
    for (int u = 0; u < 6; ++u) {                                              \
        const int p4 = l8 + 8 * u;                                             \
        if (p4 < 44) R[u] = *(const f32x4*)(s_ + p4 * 4);                      \
    }                                                                          \
}

#define DSWR(R, P) {                                                           \
    float* d_ = &strips[P][strip * WPAD];                                      \
    _Pragma("unroll")                                                          \
    for (int u = 0; u < 6; ++u) {                                              \
        const int p4 = l8 + 8 * u;                                             \
        if (p4 < 44) *(f32x4*)(d_ + p4 * 4) = R[u];                            \
    }                                                                          \
}

#define GATH(CH, P) {                                                          \
    const int ob_ = cam * CC + (CH) * CCH + cl;                                \
    for (int it2 = wv * 2; it2 < np; it2 += 8) {                               \
        const int jl = it2 + ph;                                               \
        const int jc = (jl < np) ? jl : (np - 1);                              \
        int w_, pt_;                                                           \
        if (jc < CAPM) { w_ = w_s[jc]; pt_ = pt_s[jc]; }                       \
        else { w_ = sRem[S + jc] - h * WW; pt_ = sPt[S + jc]; }                \
        const float v_ = strips[P][cl * WPAD + w_];                            \
        if (jl < np) out[(size_t)pt_ * (2 * CC) + ob_] = v_;                   \
    }                                                                          \
}

#define CHUNK_BARRIER()                                                        \
    asm volatile("s_waitcnt lgkmcnt(0)" ::: "memory");                         \
    __builtin_amdgcn_s_barrier();

__global__ __launch_bounds__(256) void k4_fused(
    const float* __restrict__ cam0, const float* __restrict__ cam1,
    const int* __restrict__ offs, const int* __restrict__ sRem,
    const int* __restrict__ sPt, float* __restrict__ out)
{
    __shared__ float strips[2][CCH * WPAD];   // 2 x 23040 B
    __shared__ int w_s[CAPM], pt_s[CAPM];     // +1536 B  => 47616 B/block

    const int tid  = threadIdx.x;
    const int lane = tid & 63, wv = tid >> 6;
    const int cl   = lane & 31, ph = lane >> 5;   // channel-lane, point-half

    const int h     = blockIdx.x & 63;
    const int bfcam = blockIdx.x >> 6;            // [0,12)
    const int cam   = (bfcam >= NBF) ? 1 : 0;
    const int bf    = bfcam - cam * NBF;
    const int b     = bf / NTF;
    const int fr    = bf - b * NTF;
    const float* img = (cam ? cam1 : cam0)
                     + (size_t)((b * TT + fr) * CC) * HW + h * WW;

    const int S  = offs[bf * BPF + h * W16];
    const int E  = offs[bf * BPF + h * W16 + W16];
    const int np = E - S;

    // point metadata -> LDS (visible after the first chunk barrier)
    for (int j = tid; j < np && j < CAPM; j += 256) {
        w_s[j]  = sRem[S + j] - h * WW;
        pt_s[j] = sPt[S + j];
    }

    const int strip = tid >> 3;   // 0..31: channel within chunk
    const int l8    = tid & 7;

    f32x4 RA[6], RB[6];

    LOADR(RA, 0)
    DSWR(RA, 0)     LOADR(RB, 1)
    CHUNK_BARRIER() GATH(0, 0)
    DSWR(RB, 1)     LOADR(RA, 2)
    CHUNK_BARRIER() GATH(1, 1)
    DSWR(RA, 0)     LOADR(RB, 3)
    CHUNK_BARRIER() GATH(2, 0)
    DSWR(RB, 1)     LOADR(RA, 4)
    CHUNK_BARRIER() GATH(3, 1)
    DSWR(RA, 0)     LOADR(RB, 5)
    CHUNK_BARRIER() GATH(4, 0)
    DSWR(RB, 1)     LOADR(RA, 6)
    CHUNK_BARRIER() GATH(5, 1)
    DSWR(RA, 0)     LOADR(RB, 7)
    CHUNK_BARRIER() GATH(6, 0)
    DSWR(RB, 1)
    CHUNK_BARRIER() GATH(7, 1)
}

// ---- K4b (fallback path): scattered gather in bucket-sorted order ---------
__global__ __launch_bounds__(256) void k4_gather(
    const float* __restrict__ cam0, const float* __restrict__ cam1,
    const int* __restrict__ sortedBase, const int* __restrict__ sortedPt,
    float* __restrict__ out)
{
    const int chunk = (blockIdx.x & 7) * (NGBLK / 8) + (blockIdx.x >> 3);
    const int c     = threadIdx.x;
    const int start = chunk * GATHER_G;

    int bases[GATHER_G], pts[GATHER_G];
#pragma unroll
    for (int g = 0; g < GATHER_G; ++g) {
        bases[g] = sortedBase[start + g];
        pts[g]   = sortedPt[start + g];
    }
    float v0[GATHER_G], v1[GATHER_G];
#pragma unroll
    for (int g = 0; g < GATHER_G; ++g) {
        v0[g] = cam0[bases[g] + c * HW];
        v1[g] = cam1[bases[g] + c * HW];
    }
#pragma unroll
    for (int g = 0; g < GATHER_G; ++g) {
        const int obase = pts[g] * (2 * CC);
        out[obase + c]      = v0[g];
        out[obase + CC + c] = v1[g];
    }
}

extern "C" void kernel_launch(void* const* d_in, const int* in_sizes, int n_in,
                              void* d_out, int out_size, void* d_ws, size_t ws_size,
                              hipStream_t stream) {
    const float* cam0 = (const float*)d_in[0];
    const float* cam1 = (const float*)d_in[1];
    // d_in[2] = anchor_centers (unused)
    const int* tIdx = (const int*)d_in[3];
    const int* sIdx = (const int*)d_in[4];
    const int* pIdx = (const int*)d_in[5];

    float* out = (float*)d_out;
    int*   ws  = (int*)d_ws;

    int* hist  = ws + WS_HIST;
    int* offs  = ws + WS_OFFS;
    int* key   = ws + WS_KEY;
    int* rank  = ws + WS_RANK;
    int* rem   = ws + WS_REM;
    int* baseA = ws + WS_BASE;
    int* sRem  = ws + WS_SREM;
    int* sBase = ws + WS_SBASE;
    int* sPt   = ws + WS_SPT;

    const int nSampled = BB * NN * PP * 2 * CC;        // 7,372,800
    const int nIdxTot  = BB * NN * (NTF + NSF + PP);   // 25,200

    // critical path: zero-hist -> prep -> scan -> scatter -> fused gather
    k0_zero<<<(NBUCKET + 255) / 256, 256, 0, stream>>>(hist);

    k1_prep<<<(NPOINTS + 255) / 256, 256, 0, stream>>>(
        tIdx, sIdx, pIdx, hist, key, rank, rem, baseA);

    k2_scan<<<1, 256, 0, stream>>>(hist, offs);

    k3_scatter<<<(NPOINTS + 255) / 256, 256, 0, stream>>>(
        key, rank, rem, baseA, offs, sRem, sBase, sPt);

    if (ws_size >= WS_MIN) {
        k4_fused<<<2 * NBF * HH, 256, 0, stream>>>(cam0, cam1, offs, sRem, sPt, out);
    } else {
        k4_gather<<<NGBLK, 256, 0, stream>>>(cam0, cam1, sBase, sPt, out);
    }

    // off critical path: index passthrough tail of out
    k0_pass<<<(nIdxTot + 255) / 256, 256, 0, stream>>>(
        tIdx, sIdx, pIdx, out + nSampled);
}

// Round 8
// 49.202 us; speedup vs baseline: 1.0370x; 1.0370x over previous
//
#include <hip/hip_runtime.h>

// Problem constants (from reference setup_inputs)
#define BB  2
#define TT  4
#define CC  256
#define HH  64
#define WW  176
#define NN  900
#define PP  8
#define NTF 3
#define NSF 3

#define HW        (HH * WW)              // 11264
#define NPOINTS   (BB * NN * PP)         // 14400
#define W16       11                     // ceil(176/16) line-buckets along w
#define NBUCKET   (BB * NTF * HH * W16)  // 4224
#define BPF       (HH * W16)             // 704 buckets per (b,frame)
#define SCAN_PER  17                     // 256*17 = 4352 >= 4224
#define GATHER_G  8
#define NGBLK     (NPOINTS / GATHER_G)   // 1800 (fallback path)
#define NBF       (BB * NTF)             // 6 (b,frame) images per cam

// fused pass: block = (cam, bf, h-row); 8 chunks of 32 channels staged in
// padded LDS; points of that (bf,h) bucket write out directly.
#define CCH    32                        // channels per chunk
#define NCH    (CC / CCH)                // 8
#define WPAD   180                       // padded strip stride (floats)
#define CAPM   192                       // cached point-meta capacity (λ≈37.5)

// native vector type
typedef float f32x4 __attribute__((ext_vector_type(4)));

// ws layout (int32 slots)
#define WS_HIST   0
#define WS_OFFS   (WS_HIST + NBUCKET)
#define WS_KEY    (WS_OFFS + NBUCKET + 1)   // +1: sentinel offs[NBUCKET]=NPOINTS
#define WS_RANK   (WS_KEY + NPOINTS)
#define WS_REM    (WS_RANK + NPOINTS)
#define WS_BASE   (WS_REM + NPOINTS)
#define WS_SREM   (WS_BASE + NPOINTS)
#define WS_SBASE  (WS_SREM + NPOINTS)
#define WS_SPT    (WS_SBASE + NPOINTS)
#define WS_INTS   (WS_SPT + NPOINTS)
#define WS_MIN    ((size_t)WS_INTS * 4)

// ---- K0: zero histogram + write index passthroughs (as float) -------------
// NOTE (round-7 lesson): do NOT split this kernel. All launches on the
// stream serialize; the passthrough work rides free inside these blocks,
// and splitting it into its own launch costs ~1.6 us.
__global__ __launch_bounds__(256) void k0_zero_idx(
    const int* __restrict__ tIdx, const int* __restrict__ sIdx,
    const int* __restrict__ pIdx, float* __restrict__ outIdx,
    int* __restrict__ hist)
{
    const int gid = blockIdx.x * 256 + threadIdx.x;
    if (gid < NBUCKET) hist[gid] = 0;
    const int nT = BB * NN * NTF, nS = BB * NN * NSF, nP = NPOINTS;
    if (gid < nT)                 outIdx[gid] = (float)tIdx[gid];
    else if (gid < nT + nS)       outIdx[gid] = (float)sIdx[gid - nT];
    else if (gid < nT + nS + nP)  outIdx[gid] = (float)pIdx[gid - nT - nS];
}

// ---- K1: decode chain, bucket key, histogram ------------------------------
__global__ __launch_bounds__(256) void k1_prep(
    const int* __restrict__ tIdx, const int* __restrict__ sIdx,
    const int* __restrict__ pIdx,
    int* __restrict__ hist, int* __restrict__ key,
    int* __restrict__ rank, int* __restrict__ remArr,
    int* __restrict__ baseArr)
{
    const int pt = blockIdx.x * 256 + threadIdx.x;
    if (pt >= NPOINTS) return;
    const int b  = pt / (NN * PP);
    const int n  = (pt - b * NN * PP) >> 3;     // / PP
    const int bn = b * NN + n;

    const int pi  = pIdx[pt];
    const int s   = pi / (NTF * HW);
    const int rem = pi % HW;                    // h*W + w
    const int h   = rem / WW;
    const int w   = rem - h * WW;

    const int sp    = sIdx[bn * NSF + s];
    const int frame = tIdx[bn * NTF + sp];

    const int base = ((b * TT + frame) * CC) * HW + rem;   // c=0 elem offset
    const int k    = ((b * NTF + frame) * HH + h) * W16 + (w >> 4);
    const int r    = atomicAdd(&hist[k], 1);
    key[pt] = k; rank[pt] = r; remArr[pt] = rem; baseArr[pt] = base;
}

// ---- K2: exclusive scan of 4224 bucket counts (single block, shfl) --------
__global__ __launch_bounds__(256) void k2_scan(
    const int* __restrict__ hist, int* __restrict__ offs)
{
    __shared__ int wsum[4];
    const int t = threadIdx.x;
    const int lane = t & 63, wv = t >> 6;
    int local[SCAN_PER];
    int sum = 0;
    for (int i = 0; i < SCAN_PER; ++i) {
        const int idx = t * SCAN_PER + i;
        const int v = (idx < NBUCKET) ? hist[idx] : 0;
        local[i] = sum;           // exclusive within this thread's chunk
        sum += v;
    }
    // wave-inclusive scan of per-thread sums
    int incl = sum;
    for (int d = 1; d < 64; d <<= 1) {
        const int up = __shfl_up(incl, d, 64);
        if (lane >= d) incl += up;
    }
    if (lane == 63) wsum[wv] = incl;
    __syncthreads();
    int wpre = 0;
    for (int k = 0; k < 4; ++k) if (k < wv) wpre += wsum[k];
    const int base = wpre + incl - sum;   // exclusive prefix of this thread
    for (int i = 0; i < SCAN_PER; ++i) {
        const int idx = t * SCAN_PER + i;
        if (idx < NBUCKET) offs[idx] = base + local[i];
    }
    if (t == 255) offs[NBUCKET] = wpre + incl;  // total = NPOINTS sentinel
}

// ---- K3: scatter points into bucket-sorted order --------------------------
__global__ __launch_bounds__(256) void k3_scatter(
    const int* __restrict__ key, const int* __restrict__ rank,
    const int* __restrict__ remArr, const int* __restrict__ baseArr,
    const int* __restrict__ offs,
    int* __restrict__ sRem, int* __restrict__ sBase, int* __restrict__ sPt)
{
    const int pt = blockIdx.x * 256 + threadIdx.x;
    if (pt >= NPOINTS) return;
    const int pos = offs[key[pt]] + rank[pt];
    sRem[pos]  = remArr[pt];
    sBase[pos] = baseArr[pt];
    sPt[pos]   = pt;
}

// ---- K4 fused: stream (cam,bf,h) strips through LDS, write out directly ---
// Block (cam, bf, h): for each of 8 chunks of 32 channels, stage the 32
// strips (176 floats each, padded to 180 to break the 16-float bank cycle)
// in a double-buffered LDS tile, then each half-wave writes one point's
// 32-channel out segment (128 B contiguous). Eliminates the compact buffer
// and the permute pass entirely: traffic 248 MB -> 168 MB.
// Register-staged loads with issue-early/write-late split; ONE raw barrier
// per chunk (double-buffer separation makes the post-gather barrier
// redundant: a wave's pre-barrier lgkmcnt(0) covers both its gather reads
// and its next-chunk ds_writes, so buffer p cannot be overwritten (chunk
// k+2) until every wave passed barrier k+1, which requires gather(k) done).

#define LOADR(R, CH) {                                                         \
    const float* s_ = img + (size_t)((CH) * CCH + strip) * HW;                 \
    _Pragma("unroll")                                                          \
    for (int u = 0; u < 6; ++u) {                                              \
        const int p4 = l8 + 8 * u;                                             \
        if (p4 < 44) R[u] = *(const f32x4*)(s_ + p4 * 4);                      \
    }                                                                          \
}

#define DSWR(R, P) {                                                           \
    float* d_ = &strips[P][strip * WPAD];                                      \
    _Pragma("unroll")                                                          \
    for (int u = 0; u < 6; ++u) {                                              \
        const int p4 = l8 + 8 * u;                                             \
        if (p4 < 44) *(f32x4*)(d_ + p4 * 4) = R[u];                            \
    }                                                                          \
}

#define GATH(CH, P) {                                                          \
    const int ob_ = cam * CC + (CH) * CCH + cl;                                \
    for (int it2 = wv * 2; it2 < np; it2 += 8) {                               \
        const int jl = it2 + ph;                                               \
        const int jc = (jl < np) ? jl : (np - 1);                              \
        int w_, pt_;                                                           \
        if (jc < CAPM) { w_ = w_s[jc]; pt_ = pt_s[jc]; }                       \
        else { w_ = sRem[S + jc] - h * WW; pt_ = sPt[S + jc]; }                \
        const float v_ = strips[P][cl * WPAD + w_];                            \
        if (jl < np) out[(size_t)pt_ * (2 * CC) + ob_] = v_;                   \
    }                                                                          \
}

#define CHUNK_BARRIER()                                                        \
    asm volatile("s_waitcnt lgkmcnt(0)" ::: "memory");                         \
    __builtin_amdgcn_s_barrier();

__global__ __launch_bounds__(256) void k4_fused(
    const float* __restrict__ cam0, const float* __restrict__ cam1,
    const int* __restrict__ offs, const int* __restrict__ sRem,
    const int* __restrict__ sPt, float* __restrict__ out)
{
    __shared__ float strips[2][CCH * WPAD];   // 2 x 23040 B
    __shared__ int w_s[CAPM], pt_s[CAPM];     // +1536 B  => 47616 B/block

    const int tid  = threadIdx.x;
    const int lane = tid & 63, wv = tid >> 6;
    const int cl   = lane & 31, ph = lane >> 5;   // channel-lane, point-half

    const int h     = blockIdx.x & 63;
    const int bfcam = blockIdx.x >> 6;            // [0,12)
    const int cam   = (bfcam >= NBF) ? 1 : 0;
    const int bf    = bfcam - cam * NBF;
    const int b     = bf / NTF;
    const int fr    = bf - b * NTF;
    const float* img = (cam ? cam1 : cam0)
                     + (size_t)((b * TT + fr) * CC) * HW + h * WW;

    const int S  = offs[bf * BPF + h * W16];
    const int E  = offs[bf * BPF + h * W16 + W16];
    const int np = E - S;

    // point metadata -> LDS (visible after the first chunk barrier)
    for (int j = tid; j < np && j < CAPM; j += 256) {
        w_s[j]  = sRem[S + j] - h * WW;
        pt_s[j] = sPt[S + j];
    }

    const int strip = tid >> 3;   // 0..31: channel within chunk
    const int l8    = tid & 7;

    f32x4 RA[6], RB[6];

    LOADR(RA, 0)
    DSWR(RA, 0)     LOADR(RB, 1)
    CHUNK_BARRIER() GATH(0, 0)
    DSWR(RB, 1)     LOADR(RA, 2)
    CHUNK_BARRIER() GATH(1, 1)
    DSWR(RA, 0)     LOADR(RB, 3)
    CHUNK_BARRIER() GATH(2, 0)
    DSWR(RB, 1)     LOADR(RA, 4)
    CHUNK_BARRIER() GATH(3, 1)
    DSWR(RA, 0)     LOADR(RB, 5)
    CHUNK_BARRIER() GATH(4, 0)
    DSWR(RB, 1)     LOADR(RA, 6)
    CHUNK_BARRIER() GATH(5, 1)
    DSWR(RA, 0)     LOADR(RB, 7)
    CHUNK_BARRIER() GATH(6, 0)
    DSWR(RB, 1)
    CHUNK_BARRIER() GATH(7, 1)
}

// ---- K4b (fallback path): scattered gather in bucket-sorted order ---------
__global__ __launch_bounds__(256) void k4_gather(
    const float* __restrict__ cam0, const float* __restrict__ cam1,
    const int* __restrict__ sortedBase, const int* __restrict__ sortedPt,
    float* __restrict__ out)
{
    const int chunk = (blockIdx.x & 7) * (NGBLK / 8) + (blockIdx.x >> 3);
    const int c     = threadIdx.x;
    const int start = chunk * GATHER_G;

    int bases[GATHER_G], pts[GATHER_G];
#pragma unroll
    for (int g = 0; g < GATHER_G; ++g) {
        bases[g] = sortedBase[start + g];
        pts[g]   = sortedPt[start + g];
    }
    float v0[GATHER_G], v1[GATHER_G];
#pragma unroll
    for (int g = 0; g < GATHER_G; ++g) {
        v0[g] = cam0[bases[g] + c * HW];
        v1[g] = cam1[bases[g] + c * HW];
    }
#pragma unroll
    for (int g = 0; g < GATHER_G; ++g) {
        const int obase = pts[g] * (2 * CC);
        out[obase + c]      = v0[g];
        out[obase + CC + c] = v1[g];
    }
}

extern "C" void kernel_launch(void* const* d_in, const int* in_sizes, int n_in,
                              void* d_out, int out_size, void* d_ws, size_t ws_size,
                              hipStream_t stream) {
    const float* cam0 = (const float*)d_in[0];
    const float* cam1 = (const float*)d_in[1];
    // d_in[2] = anchor_centers (unused)
    const int* tIdx = (const int*)d_in[3];
    const int* sIdx = (const int*)d_in[4];
    const int* pIdx = (const int*)d_in[5];

    float* out = (float*)d_out;
    int*   ws  = (int*)d_ws;

    int* hist  = ws + WS_HIST;
    int* offs  = ws + WS_OFFS;
    int* key   = ws + WS_KEY;
    int* rank  = ws + WS_RANK;
    int* rem   = ws + WS_REM;
    int* baseA = ws + WS_BASE;
    int* sRem  = ws + WS_SREM;
    int* sBase = ws + WS_SBASE;
    int* sPt   = ws + WS_SPT;

    const int nSampled = BB * NN * PP * 2 * CC;        // 7,372,800
    const int nIdxTot  = BB * NN * (NTF + NSF + PP);   // 25,200

    k0_zero_idx<<<(nIdxTot + 255) / 256, 256, 0, stream>>>(
        tIdx, sIdx, pIdx, out + nSampled, hist);

    k1_prep<<<(NPOINTS + 255) / 256, 256, 0, stream>>>(
        tIdx, sIdx, pIdx, hist, key, rank, rem, baseA);

    k2_scan<<<1, 256, 0, stream>>>(hist, offs);

    k3_scatter<<<(NPOINTS + 255) / 256, 256, 0, stream>>>(
        key, rank, rem, baseA, offs, sRem, sBase, sPt);

    if (ws_size >= WS_MIN) {
        k4_fused<<<2 * NBF * HH, 256, 0, stream>>>(cam0, cam1, offs, sRem, sPt, out);
    } else {
        k4_gather<<<NGBLK, 256, 0, stream>>>(cam0, cam1, sBase, sPt, out);
    }
}